// Round 11
// baseline (761.347 us; speedup 1.0000x reference)
//
#include <hip/hip_runtime.h>
#include <cstdint>

#define NT 8192
#define DD 1024
#define NE 8
#define BK 32
#define NKIT (DD / BK)
#define TM 128                 // m-tile
#define MAXTILE 72             // sum ceil(c/128) <= 8192/128 + 8
#define TPX (MAXTILE / 8)      // tiles per XCD = 9
#define GRID 576               // 72 tiles x 8 n-blocks; 3 blocks/CU co-resident (48KB LDS)

typedef __attribute__((ext_vector_type(8))) _Float16 half8;
typedef __attribute__((ext_vector_type(4))) float f32x4;

__device__ __forceinline__ unsigned short f2h_bits(float f) {
  _Float16 h = (_Float16)f;
  return __builtin_bit_cast(unsigned short, h);
}

// async global->LDS, 16B per lane. LDS dest must be wave-uniform base + lane*16;
// the GLOBAL address is an ordinary per-lane VGPR address (indirection is fine).
#define GLDS16(gp, lp) __builtin_amdgcn_global_load_lds( \
  (__attribute__((address_space(1))) void*)(uintptr_t)(gp), \
  (__attribute__((address_space(3))) void*)(uintptr_t)(lp), 16, 0, 0)

// s_waitcnt imm (gfx9): vmcnt[3:0]|[15:14], expcnt[6:4], lgkmcnt[11:8]; 0xF70|N = vmcnt(N) only
#define WAITCNT_VM4  0xF74
#define WAITCNT_VM0  0xF70

// ---------------- manual grid barrier (R10 postmortem: hipLaunchCooperativeKernel is not
// graph-capturable in this harness -> empty graph -> zero output). All 576 blocks are
// co-resident (3 blocks/CU by LDS+launch_bounds), so a software barrier is sound.
// Release side: every thread fences (vmcnt drain + XCD-L2 writeback) before arrive.
// Acquire side: every thread fences after the spin (invalidate stale lines). ----------------
__device__ __forceinline__ void gridbar(unsigned* bar, unsigned target) {
  __threadfence();
  __syncthreads();
  if (threadIdx.x == 0) {
    __hip_atomic_fetch_add(bar, 1u, __ATOMIC_ACQ_REL, __HIP_MEMORY_SCOPE_AGENT);
    while (__hip_atomic_load(bar, __ATOMIC_RELAXED, __HIP_MEMORY_SCOPE_AGENT) < target) {
      __builtin_amdgcn_s_sleep(2);
    }
  }
  __syncthreads();
  __threadfence();
}

// ---------------- job: weight cast+transpose, one 64x64 tile. j in [0,2048): e=j>>8 ----------------
__device__ void wcast_job(const float* __restrict__ W, _Float16* __restrict__ Wt,
                          int j, int tid, char* smem) {
  float (*tile)[65] = (float (*)[65])smem;     // 64 x 65 floats = 16.6 KB
  const float* Ws = W + (size_t)(j >> 8) * (DD * DD);
  _Float16* Wd    = Wt + (size_t)(j >> 8) * (DD * DD);
  const int k0 = ((j >> 4) & 15) * 64, n0 = (j & 15) * 64;
#pragma unroll
  for (int it = 0; it < 4; ++it) {
    int idx = it * 256 + tid;                  // 0..1023
    int r = idx >> 4;                          // k-row 0..63
    int q = idx & 15;                          // float4 col
    float4 v = *(const float4*)(Ws + (size_t)(k0 + r) * DD + n0 + q * 4);
    tile[r][q * 4 + 0] = v.x; tile[r][q * 4 + 1] = v.y;
    tile[r][q * 4 + 2] = v.z; tile[r][q * 4 + 3] = v.w;
  }
  __syncthreads();
#pragma unroll
  for (int it = 0; it < 4; ++it) {
    int idx = it * 256 + tid;
    int n = idx >> 4;                          // out row (n) 0..63
    int q = idx & 15;                          // k 4-chunk
    ushort4 o;
    o.x = f2h_bits(tile[q * 4 + 0][n]);
    o.y = f2h_bits(tile[q * 4 + 1][n]);
    o.z = f2h_bits(tile[q * 4 + 2][n]);
    o.w = f2h_bits(tile[q * 4 + 3][n]);
    *(ushort4*)(Wd + (size_t)(n0 + n) * DD + k0 + q * 4) = o;
  }
}

// ---------------- job: gating for 8 tokens (t = j*8 .. j*8+7); also emits xh = fp16(x) ----------------
__device__ void gate_job(const float* __restrict__ x, const float* __restrict__ Wg,
                         const float* __restrict__ bg, int* __restrict__ assign,
                         float* __restrict__ wgt, _Float16* __restrict__ xh,
                         int j, int tid, char* smem) {
  float* WgL = (float*)smem;                   // NE*DD floats = 32 KB, e-major
#pragma unroll
  for (int it = 0; it < 8; ++it) {
    int idx = it * 256 + tid;                  // float4 index 0..2047
    float4 v = ((const float4*)Wg)[idx];
    int k = idx >> 1;
    int e0 = (idx & 1) * 4;
    WgL[(e0 + 0) * DD + k] = v.x;
    WgL[(e0 + 1) * DD + k] = v.y;
    WgL[(e0 + 2) * DD + k] = v.z;
    WgL[(e0 + 3) * DD + k] = v.w;
  }
  __syncthreads();
  const int lane = tid & 63, w = tid >> 6;
#pragma unroll
  for (int s = 0; s < 2; ++s) {
    const int t = j * 8 + w * 2 + s;
    const float4* xr = (const float4*)(x + (size_t)t * DD);
    float4 xv[4];
#pragma unroll
    for (int c = 0; c < 4; ++c) xv[c] = xr[lane + 64 * c];
    ushort4* xo = (ushort4*)(xh + (size_t)t * DD);
#pragma unroll
    for (int c = 0; c < 4; ++c) {
      union { ushort4 u; _Float16 h[4]; } cv;
      cv.h[0] = (_Float16)xv[c].x; cv.h[1] = (_Float16)xv[c].y;
      cv.h[2] = (_Float16)xv[c].z; cv.h[3] = (_Float16)xv[c].w;
      xo[lane + 64 * c] = cv.u;
    }
    float p[NE];
#pragma unroll
    for (int e = 0; e < NE; ++e) {
      float acc = 0.f;
#pragma unroll
      for (int c = 0; c < 4; ++c) {
        float4 wv = *(const float4*)&WgL[e * DD + 4 * lane + 256 * c];
        acc += xv[c].x * wv.x + xv[c].y * wv.y + xv[c].z * wv.z + xv[c].w * wv.w;
      }
      p[e] = acc;
    }
#pragma unroll
    for (int e = 0; e < NE; ++e) {
      float v = p[e];
      for (int off = 32; off > 0; off >>= 1) v += __shfl_down(v, off, 64);
      p[e] = v;
    }
    if (lane == 0) {
      float l[NE];
#pragma unroll
      for (int e = 0; e < NE; ++e) l[e] = p[e] + bg[e];
      int a = 0; float best = l[0];
#pragma unroll
      for (int e = 1; e < NE; ++e) if (l[e] > best) { best = l[e]; a = e; }
      float sum = 0.f;
#pragma unroll
      for (int e = 0; e < NE; ++e) sum += expf(l[e] - best);
      assign[t] = a;
      wgt[t] = 1.0f / sum;
    }
  }
}

// ---------------- sort (block 0, 256 threads, 32 tokens/thread): register shuffle scan ----------------
// Deterministic order: token position = global exclusive prefix per expert, thread-major.
__device__ void sort_256(const int* __restrict__ assign, int* __restrict__ rowtok,
                         int* __restrict__ plan, int tid, char* smem) {
  int (*wsum)[NE] = (int (*)[NE])smem;         // 4 x 8 ints
  const int lane = tid & 63, wv = tid >> 6;    // 4 waves
  int a[32];
  int c[NE];
#pragma unroll
  for (int e = 0; e < NE; ++e) c[e] = 0;
#pragma unroll
  for (int j = 0; j < 32; ++j) { a[j] = assign[tid * 32 + j]; ++c[a[j]]; }
  int inc[NE];
#pragma unroll
  for (int e = 0; e < NE; ++e) inc[e] = c[e];
  for (int d = 1; d < 64; d <<= 1) {
#pragma unroll
    for (int e = 0; e < NE; ++e) {
      int u = __shfl_up(inc[e], d, 64);
      if (lane >= d) inc[e] += u;
    }
  }
  if (lane == 63) {
#pragma unroll
    for (int e = 0; e < NE; ++e) wsum[wv][e] = inc[e];
  }
  __syncthreads();
  int wb[NE], tote[NE];
#pragma unroll
  for (int e = 0; e < NE; ++e) {
    int s = 0, t = 0;
#pragma unroll
    for (int w = 0; w < 4; ++w) { int v = wsum[w][e]; if (w < wv) s += v; t += v; }
    wb[e] = s; tote[e] = t;
  }
  int offs[NE];
  {
    int s = 0;
#pragma unroll
    for (int e = 0; e < NE; ++e) { offs[e] = s; s += tote[e]; }
  }
  int run[NE];
#pragma unroll
  for (int e = 0; e < NE; ++e) run[e] = offs[e] + wb[e] + inc[e] - c[e];
#pragma unroll
  for (int j = 0; j < 32; ++j) { int e = a[j]; rowtok[run[e]++] = tid * 32 + j; }
  int pref[NE + 1];
  {
    int s = 0;
#pragma unroll
    for (int e = 0; e < NE; ++e) { pref[e] = s; s += (tote[e] + TM - 1) / TM; }
    pref[NE] = s;
  }
  if (tid == 0) plan[0] = pref[NE];
  if (tid < pref[NE]) {
    int e = 0;
    while (tid >= pref[e + 1]) ++e;
    int t = tid - pref[e];
    plan[1 + tid] = e;
    plan[1 + MAXTILE + tid] = offs[e] + t * TM;
    plan[1 + 2 * MAXTILE + tid] = offs[e] + tote[e];
  }
}

// ---------------- gemm phase: R5's proven 128x128 / 4-wave / 3-buffer body, verbatim ----------------
// MODE 0: H[p] = gelu_exact(xh[rowtok[p]] @ W1t^T + b1)  -> fp16
// MODE 1: out[rowtok[p]] = (H[p] @ W2t^T + b2) * wgt      -> fp32 scatter
template <int MODE>
__device__ void gemm_phase(int wrk,
    const _Float16* __restrict__ A, const _Float16* __restrict__ Wt,
    const float* __restrict__ bias, const int* __restrict__ plan,
    _Float16* __restrict__ Hout, float* __restrict__ Fout,
    const int* __restrict__ rowtok, const float* __restrict__ wgt, char* lds) {
  const int g = wrk & 7;               // XCD (bid%8 round-robin)
  const int r = wrk >> 3;              // 0..71
  const int tile = g * TPX + (r >> 3);
  const int nb = r & 7;
  if (tile >= plan[0]) return;         // device-fn return: caller still reaches gridbar
  const int e = plan[1 + tile];
  const int m0 = plan[1 + MAXTILE + tile];
  const int seg_end = plan[1 + 2 * MAXTILE + tile];
  const int n0 = nb * 128;

  const int tid = threadIdx.x;
  const int lane = tid & 63;
  const int wv = tid >> 6;             // wave 0..3
  const int wm = wv >> 1;              // m half 0..1 (64 rows)
  const int wq = wv & 1;               // n half 0..1 (64 cols)
  const int quad = lane >> 4;
  const int r15 = lane & 15;

  const _Float16* We = Wt + (size_t)e * DD * DD;
  const _Float16* gAp[2];
  const _Float16* gBp[2];
  int ldsoA[2], ldsoB[2];
#pragma unroll
  for (int i = 0; i < 2; ++i) {
    int slot = i * 256 + tid;
    int row = slot >> 2;               // 0..127
    int c = (slot & 3) ^ ((row >> 1) & 3);
    int rg = m0 + row; if (rg > NT - 1) rg = NT - 1;
    int arow = (MODE == 0) ? rowtok[rg] : rg;
    gAp[i] = A + (size_t)arow * DD + c * 8;
    ldsoA[i] = slot * 16;
    gBp[i] = We + (size_t)(n0 + row) * DD + c * 8;
    ldsoB[i] = slot * 16;
  }

  int aoff[4], boff[4];
#pragma unroll
  for (int i = 0; i < 4; ++i) {
    int m = wm * 64 + i * 16 + r15;
    aoff[i] = m * 4 + (quad ^ ((m >> 1) & 3));
    int n = wq * 64 + i * 16 + r15;
    boff[i] = n * 4 + (quad ^ ((n >> 1) & 3));
  }

  f32x4 acc[4][4];
  f32x4 zero4 = {0.f, 0.f, 0.f, 0.f};
#pragma unroll
  for (int mi = 0; mi < 4; ++mi)
#pragma unroll
    for (int ni = 0; ni < 4; ++ni) acc[mi][ni] = zero4;

#define LDSBUF(B) (lds + (B) * 16384)
#define STAGE(KT, BUF) do {                                          \
    const int ko_ = (KT) * BK;                                       \
    char* lb_ = LDSBUF(BUF);                                         \
    GLDS16(gAp[0] + ko_, lb_ + ldsoA[0]);                            \
    GLDS16(gAp[1] + ko_, lb_ + ldsoA[1]);                            \
    GLDS16(gBp[0] + ko_, lb_ + 8192 + ldsoB[0]);                     \
    GLDS16(gBp[1] + ko_, lb_ + 8192 + ldsoB[1]);                     \
  } while (0)
#define COMPUTE(BUF) do {                                            \
    const half8* AsV = (const half8*)(LDSBUF(BUF));                  \
    const half8* BsV = (const half8*)(LDSBUF(BUF) + 8192);           \
    half8 a_[4], b_[4];                                              \
    _Pragma("unroll")                                                \
    for (int i = 0; i < 4; ++i) a_[i] = AsV[aoff[i]];                \
    _Pragma("unroll")                                                \
    for (int i = 0; i < 4; ++i) b_[i] = BsV[boff[i]];                \
    _Pragma("unroll")                                                \
    for (int mi = 0; mi < 4; ++mi)                                   \
      _Pragma("unroll")                                              \
      for (int ni = 0; ni < 4; ++ni)                                 \
        acc[mi][ni] = __builtin_amdgcn_mfma_f32_16x16x32_f16(a_[mi], b_[ni], acc[mi][ni], 0, 0, 0); \
  } while (0)

  STAGE(0, 0);
  STAGE(1, 1);

#pragma unroll 1
  for (int kt = 0; kt < NKIT - 2; kt += 3) {
    __builtin_amdgcn_s_waitcnt(WAITCNT_VM4);
    __builtin_amdgcn_s_barrier();
    __asm__ volatile("" ::: "memory");
    STAGE(kt + 2, 2);
    COMPUTE(0);
    __builtin_amdgcn_s_waitcnt(WAITCNT_VM4);
    __builtin_amdgcn_s_barrier();
    __asm__ volatile("" ::: "memory");
    STAGE(kt + 3, 0);
    COMPUTE(1);
    __builtin_amdgcn_s_waitcnt(WAITCNT_VM4);
    __builtin_amdgcn_s_barrier();
    __asm__ volatile("" ::: "memory");
    STAGE(kt + 4, 1);
    COMPUTE(2);
  }
  __builtin_amdgcn_s_waitcnt(WAITCNT_VM4);
  __builtin_amdgcn_s_barrier();
  __asm__ volatile("" ::: "memory");
  COMPUTE(0);
  __builtin_amdgcn_s_waitcnt(WAITCNT_VM0);
  __builtin_amdgcn_s_barrier();
  __asm__ volatile("" ::: "memory");
  COMPUTE(1);
#undef COMPUTE
#undef STAGE
#undef LDSBUF

  const float* bptr = bias + (size_t)e * DD;
#pragma unroll
  for (int mi = 0; mi < 4; ++mi) {
    int rowb = m0 + wm * 64 + mi * 16 + quad * 4;
#pragma unroll
    for (int rr = 0; rr < 4; ++rr) {
      int gpos = rowb + rr;
      if (gpos < seg_end) {
        if (MODE == 0) {
#pragma unroll
          for (int ni = 0; ni < 4; ++ni) {
            int n = n0 + wq * 64 + ni * 16 + r15;
            float val = acc[mi][ni][rr] + bptr[n];
            val = 0.5f * val * (1.0f + erff(val * 0.70710678118654752f));
            Hout[(size_t)gpos * DD + n] = (_Float16)val;
          }
        } else {
          int tok = rowtok[gpos];
          float wgl = wgt[tok];
          float* orow = Fout + (size_t)tok * DD;
#pragma unroll
          for (int ni = 0; ni < 4; ++ni) {
            int n = n0 + wq * 64 + ni * 16 + r15;
            orow[n] = (acc[mi][ni][rr] + bptr[n]) * wgl;
          }
        }
      }
    }
  }
}

// ---------------- fused pipeline: one NORMAL kernel, 4 phases, 3 software grid barriers ----------------
// P1: gate (1024 jobs) + W1-cast (2048 jobs) over 576 blocks. P2: block 0 sorts (register
// scan) while blocks 1..575 do the W2-cast -> sort hidden. P3: gemm0 (R5 body). P4: gemm1.
// Every block executes exactly 3 gridbars (no early return in this function).
__global__ __launch_bounds__(256, 3) void fused_kernel(
    const float* __restrict__ x, const float* __restrict__ Wg, const float* __restrict__ bg,
    const float* __restrict__ W1, const float* __restrict__ b1,
    const float* __restrict__ W2, const float* __restrict__ b2,
    float* __restrict__ out,
    _Float16* __restrict__ W1t, _Float16* __restrict__ W2t,
    _Float16* __restrict__ xh, _Float16* __restrict__ H,
    int* __restrict__ assign, int* __restrict__ rowtok,
    float* __restrict__ wgt, int* __restrict__ plan, unsigned* __restrict__ bars) {
  __shared__ alignas(16) char smem[49152];     // 48 KB -> 3 blocks/CU, grid 576 <= 768 resident
  const int bid = blockIdx.x;
  const int tid = threadIdx.x;

  // ---- P1: gate (jobs 0..1023) + W1 cast (jobs 1024..3071) ----
  for (int j = bid; j < 3072; j += GRID) {
    if (j < 1024) gate_job(x, Wg, bg, assign, wgt, xh, j, tid, smem);
    else          wcast_job(W1, W1t, j - 1024, tid, smem);
    __syncthreads();                           // smem reuse between jobs
  }
  gridbar(bars + 0, GRID);

  // ---- P2: sort (block 0) || W2 cast (blocks 1..575, 2048 jobs) ----
  if (bid == 0) {
    sort_256(assign, rowtok, plan, tid, smem);
  } else {
    for (int j = bid - 1; j < 2048; j += GRID - 1) {
      wcast_job(W2, W2t, j, tid, smem);
      __syncthreads();
    }
  }
  gridbar(bars + 1, GRID);

  // ---- P3: gemm0 ----
  gemm_phase<0>(bid, xh, W1t, b1, plan, H, nullptr, rowtok, nullptr, smem);
  gridbar(bars + 2, GRID);

  // ---- P4: gemm1 ----
  gemm_phase<1>(bid, H, W2t, b2, plan, nullptr, out, rowtok, wgt, smem);
}

extern "C" void kernel_launch(void* const* d_in, const int* in_sizes, int n_in,
                              void* d_out, int out_size, void* d_ws, size_t ws_size,
                              hipStream_t stream) {
  const float* x  = (const float*)d_in[0];
  const float* Wg = (const float*)d_in[1];
  const float* bg = (const float*)d_in[2];
  const float* W1 = (const float*)d_in[3];
  const float* b1 = (const float*)d_in[4];
  const float* W2 = (const float*)d_in[5];
  const float* b2 = (const float*)d_in[6];
  float* out = (float*)d_out;

  char* ws = (char*)d_ws;
  const size_t MB16 = (size_t)1 << 24;
  _Float16* W1t = (_Float16*)(ws + 0 * MB16);
  _Float16* W2t = (_Float16*)(ws + 1 * MB16);
  _Float16* xh  = (_Float16*)(ws + 2 * MB16);
  _Float16* H   = (_Float16*)(ws + 3 * MB16);
  int*   assign = (int*)(ws + 4 * MB16);
  int*   rowtok = assign + NT;
  float* wgt    = (float*)(rowtok + NT);
  int*   plan   = (int*)(wgt + NT);    // [1 + 3*MAXTILE]
  unsigned* bars = (unsigned*)(plan + 512);  // 3 barrier counters, zeroed per launch

  hipMemsetAsync(bars, 0, 64, stream);
  fused_kernel<<<GRID, 256, 0, stream>>>(x, Wg, bg, W1, b1, W2, b2, out,
                                         W1t, W2t, xh, H, assign, rowtok, wgt, plan, bars);
}

// Round 12
// 272.089 us; speedup vs baseline: 2.7982x; 2.7982x over previous
//
#include <hip/hip_runtime.h>
#include <cstdint>

#define NT 8192
#define DD 1024
#define NE 8
#define BK 32
#define NKIT (DD / BK)
#define TM 128                 // m-tile
#define MAXTILE 72             // sum ceil(c/128) <= 8192/128 + 8
#define TPX (MAXTILE / 8)      // tiles per XCD = 9

typedef __attribute__((ext_vector_type(8))) _Float16 half8;
typedef __attribute__((ext_vector_type(4))) float f32x4;

__device__ __forceinline__ unsigned short f2h_bits(float f) {
  _Float16 h = (_Float16)f;
  return __builtin_bit_cast(unsigned short, h);
}

// async global->LDS, 16B per lane. LDS dest must be wave-uniform base + lane*16;
// the GLOBAL address is an ordinary per-lane VGPR address (indirection is fine).
#define GLDS16(gp, lp) __builtin_amdgcn_global_load_lds( \
  (__attribute__((address_space(1))) void*)(uintptr_t)(gp), \
  (__attribute__((address_space(3))) void*)(uintptr_t)(lp), 16, 0, 0)

// s_waitcnt imm (gfx9): vmcnt[3:0]|[15:14], expcnt[6:4], lgkmcnt[11:8]; 0xF70|N = vmcnt(N) only
#define WAITCNT_VM4  0xF74
#define WAITCNT_VM0  0xF70

// ---------------- fused prep: wcast (blocks 0..4095) + gate (blocks 4096..5119) ----------------
__global__ __launch_bounds__(256) void prep_kernel(
    const float* __restrict__ W1, const float* __restrict__ W2,
    _Float16* __restrict__ W1t, _Float16* __restrict__ W2t,
    const float* __restrict__ x, const float* __restrict__ Wg, const float* __restrict__ bg,
    int* __restrict__ assign, float* __restrict__ wgt, _Float16* __restrict__ xh) {
  __shared__ alignas(16) char smem[32768];
  const int bid = blockIdx.x;
  const int tid = threadIdx.x;
  if (bid < 4096) {
    // ---- wcast path: fp32 [e][k][n] -> fp16 [e][n][k] ----
    float (*tile)[65] = (float (*)[65])smem;   // 64 x 65 floats = 16.6 KB
    const int z = bid >> 8;                    // 0..15: [0,8)=W1, [8,16)=W2
    const float* W = (z < 8 ? W1 : W2) + (size_t)(z & 7) * (DD * DD);
    _Float16* Wt   = (z < 8 ? W1t : W2t) + (size_t)(z & 7) * (DD * DD);
    const int k0 = (bid & 15) * 64, n0 = ((bid >> 4) & 15) * 64;
#pragma unroll
    for (int it = 0; it < 4; ++it) {
      int idx = it * 256 + tid;                // 0..1023
      int r = idx >> 4;                        // k-row 0..63
      int q = idx & 15;                        // float4 col
      float4 v = *(const float4*)(W + (size_t)(k0 + r) * DD + n0 + q * 4);
      tile[r][q * 4 + 0] = v.x; tile[r][q * 4 + 1] = v.y;
      tile[r][q * 4 + 2] = v.z; tile[r][q * 4 + 3] = v.w;
    }
    __syncthreads();
#pragma unroll
    for (int it = 0; it < 4; ++it) {
      int idx = it * 256 + tid;
      int n = idx >> 4;                        // out row (n) 0..63
      int q = idx & 15;                        // k 4-chunk
      ushort4 o;
      o.x = f2h_bits(tile[q * 4 + 0][n]);
      o.y = f2h_bits(tile[q * 4 + 1][n]);
      o.z = f2h_bits(tile[q * 4 + 2][n]);
      o.w = f2h_bits(tile[q * 4 + 3][n]);
      *(ushort4*)(Wt + (size_t)(n0 + n) * DD + k0 + q * 4) = o;
    }
  } else {
    // ---- gate path ----
    float* WgL = (float*)smem;                 // NE*DD floats = 32 KB, e-major
    const int gb = bid - 4096;                 // 0..1023
#pragma unroll
    for (int it = 0; it < 8; ++it) {
      int idx = it * 256 + tid;                // float4 index 0..2047
      float4 v = ((const float4*)Wg)[idx];
      int k = idx >> 1;
      int e0 = (idx & 1) * 4;
      WgL[(e0 + 0) * DD + k] = v.x;
      WgL[(e0 + 1) * DD + k] = v.y;
      WgL[(e0 + 2) * DD + k] = v.z;
      WgL[(e0 + 3) * DD + k] = v.w;
    }
    __syncthreads();
    const int lane = tid & 63, w = tid >> 6;
#pragma unroll
    for (int s = 0; s < 2; ++s) {
      const int t = gb * 8 + w * 2 + s;
      const float4* xr = (const float4*)(x + (size_t)t * DD);
      float4 xv[4];
#pragma unroll
      for (int c = 0; c < 4; ++c) xv[c] = xr[lane + 64 * c];
      ushort4* xo = (ushort4*)(xh + (size_t)t * DD);
#pragma unroll
      for (int c = 0; c < 4; ++c) {
        union { ushort4 u; _Float16 h[4]; } cv;
        cv.h[0] = (_Float16)xv[c].x; cv.h[1] = (_Float16)xv[c].y;
        cv.h[2] = (_Float16)xv[c].z; cv.h[3] = (_Float16)xv[c].w;
        xo[lane + 64 * c] = cv.u;
      }
      float p[NE];
#pragma unroll
      for (int e = 0; e < NE; ++e) {
        float acc = 0.f;
#pragma unroll
        for (int c = 0; c < 4; ++c) {
          float4 wv = *(const float4*)&WgL[e * DD + 4 * lane + 256 * c];
          acc += xv[c].x * wv.x + xv[c].y * wv.y + xv[c].z * wv.z + xv[c].w * wv.w;
        }
        p[e] = acc;
      }
#pragma unroll
      for (int e = 0; e < NE; ++e) {
        float v = p[e];
        for (int off = 32; off > 0; off >>= 1) v += __shfl_down(v, off, 64);
        p[e] = v;
      }
      if (lane == 0) {
        float l[NE];
#pragma unroll
        for (int e = 0; e < NE; ++e) l[e] = p[e] + bg[e];
        int a = 0; float best = l[0];
#pragma unroll
        for (int e = 1; e < NE; ++e) if (l[e] > best) { best = l[e]; a = e; }
        float sum = 0.f;
#pragma unroll
        for (int e = 0; e < NE; ++e) sum += expf(l[e] - best);
        assign[t] = a;
        wgt[t] = 1.0f / sum;
      }
    }
  }
}

// ---------------- grouped GEMM with replicated in-block sort prologue ----------------
// R11 post-mortem: software grid barrier = ~160us/barrier on MI355X (576-way device-scope
// atomic RMW contention + per-wave threadfence L2 writeback across 8 non-coherent L2s) ->
// fused single-kernel is 638us vs 130us of work. Fusion refuted. Salvage: the counting sort
// is a pure function of assign[] and cheap (~4us of register-scan), so REPLICATE it in every
// gemm block as a prologue -> the sort kernel and its launch boundary disappear. Each block
// derives tote/offs/plan in registers (identical in all blocks, deterministic) and scatters
// only its own tile's 128-entry rowtok slice into LDS (+512B, still 3 blocks/CU).
// Gemm body = R5/R9 proven config verbatim (128x128, 4 waves 64x64, 3-buffer depth-2,
// XCD-swizzled: FETCH 75->22MB, 47us).
// MODE 0: H[p] = gelu_exact(xh[rowtok[p]] @ W1t^T + b1)  -> fp16
// MODE 1: out[rowtok[p]] = (H[p] @ W2t^T + b2) * wgt      -> fp32 scatter
template <int MODE>
__global__ __launch_bounds__(256, 3) void gemm_kernel(
    const _Float16* __restrict__ A,
    const _Float16* __restrict__ Wt,
    const float* __restrict__ bias,
    const int* __restrict__ assign,
    _Float16* __restrict__ Hout,
    float* __restrict__ Fout,
    const float* __restrict__ wgt) {
  // LDS: 3 gemm buffers (48KB) + rowtok slice (512B) + wsum scratch (128B)
  __shared__ alignas(16) char lds[50176];
  int* rowtok_lds = (int*)(lds + 49152);       // [TM] token index per tile row
  int (*wsum)[NE] = (int (*)[NE])(lds + 49152 + TM * 4);

  const int tid = threadIdx.x;
  const int lane = tid & 63;
  const int wv = tid >> 6;             // wave 0..3

  // ---- sort prologue: 32 tokens/thread, wave shuffle-scan, stable by token index ----
  int at[32];
  int c[NE];
#pragma unroll
  for (int e = 0; e < NE; ++e) c[e] = 0;
#pragma unroll
  for (int j = 0; j < 32; ++j) { at[j] = assign[tid * 32 + j]; ++c[at[j]]; }
  int inc[NE];
#pragma unroll
  for (int e = 0; e < NE; ++e) inc[e] = c[e];
  for (int d = 1; d < 64; d <<= 1) {
#pragma unroll
    for (int e = 0; e < NE; ++e) {
      int u = __shfl_up(inc[e], d, 64);
      if (lane >= d) inc[e] += u;
    }
  }
  if (lane == 63) {
#pragma unroll
    for (int e = 0; e < NE; ++e) wsum[wv][e] = inc[e];
  }
  if (tid < TM) rowtok_lds[tid] = 0;   // rows past the last global position stay token 0 (safe)
  __syncthreads();
  int wb[NE], tote[NE];
#pragma unroll
  for (int e = 0; e < NE; ++e) {
    int s = 0, t = 0;
#pragma unroll
    for (int w = 0; w < 4; ++w) { int v = wsum[w][e]; if (w < wv) s += v; t += v; }
    wb[e] = s; tote[e] = t;
  }
  int offs[NE];
  {
    int s = 0;
#pragma unroll
    for (int e = 0; e < NE; ++e) { offs[e] = s; s += tote[e]; }
  }
  int pref[NE + 1];
  {
    int s = 0;
#pragma unroll
    for (int e = 0; e < NE; ++e) { pref[e] = s; s += (tote[e] + TM - 1) / TM; }
    pref[NE] = s;
  }

  // block -> (tile, nb) with XCD-aware bijection (g = bid%8 round-robin XCD)
  const int wrk = blockIdx.x;
  const int g = wrk & 7;
  const int r = wrk >> 3;              // 0..71
  const int tile = g * TPX + (r >> 3);
  const int nb = r & 7;
  if (tile >= pref[NE]) return;        // block-uniform: whole block exits, no barrier hazard
  int eid = 0;
#pragma unroll
  for (int e = 0; e < NE; ++e) if (tile >= pref[e + 1]) eid = e + 1;
  const int m0 = offs[eid] + (tile - pref[eid]) * TM;
  const int seg_end = offs[eid] + tote[eid];
  const int n0 = nb * 128;

  // scatter: my tokens whose global position lands in this tile's window
  {
    int run[NE];
#pragma unroll
    for (int e = 0; e < NE; ++e) run[e] = offs[e] + wb[e] + inc[e] - c[e];
#pragma unroll
    for (int j = 0; j < 32; ++j) {
      int e = at[j];
      int p = run[e]++;
      int rel = p - m0;
      if ((unsigned)rel < (unsigned)TM) rowtok_lds[rel] = tid * 32 + j;
    }
  }
  __syncthreads();

  // ---- gemm body (R5 verbatim, rowtok via LDS slice) ----
  const int wm = wv >> 1;              // m half 0..1 (64 rows)
  const int wq = wv & 1;               // n half 0..1 (64 cols)
  const int quad = lane >> 4;
  const int r15 = lane & 15;

  const _Float16* We = Wt + (size_t)eid * DD * DD;
  const _Float16* gAp[2];
  const _Float16* gBp[2];
  int ldsoA[2], ldsoB[2];
#pragma unroll
  for (int i = 0; i < 2; ++i) {
    int slot = i * 256 + tid;
    int row = slot >> 2;               // 0..127
    int cc = (slot & 3) ^ ((row >> 1) & 3);
    int arow;
    if (MODE == 0) {
      arow = rowtok_lds[row];
    } else {
      int rg = m0 + row; if (rg > NT - 1) rg = NT - 1;
      arow = rg;
    }
    gAp[i] = A + (size_t)arow * DD + cc * 8;
    ldsoA[i] = slot * 16;
    gBp[i] = We + (size_t)(n0 + row) * DD + cc * 8;
    ldsoB[i] = slot * 16;
  }

  int aoff[4], boff[4];
#pragma unroll
  for (int i = 0; i < 4; ++i) {
    int m = wm * 64 + i * 16 + r15;
    aoff[i] = m * 4 + (quad ^ ((m >> 1) & 3));
    int n = wq * 64 + i * 16 + r15;
    boff[i] = n * 4 + (quad ^ ((n >> 1) & 3));
  }

  f32x4 acc[4][4];
  f32x4 zero4 = {0.f, 0.f, 0.f, 0.f};
#pragma unroll
  for (int mi = 0; mi < 4; ++mi)
#pragma unroll
    for (int ni = 0; ni < 4; ++ni) acc[mi][ni] = zero4;

#define LDSBUF(B) (lds + (B) * 16384)
#define STAGE(KT, BUF) do {                                          \
    const int ko_ = (KT) * BK;                                       \
    char* lb_ = LDSBUF(BUF);                                         \
    GLDS16(gAp[0] + ko_, lb_ + ldsoA[0]);                            \
    GLDS16(gAp[1] + ko_, lb_ + ldsoA[1]);                            \
    GLDS16(gBp[0] + ko_, lb_ + 8192 + ldsoB[0]);                     \
    GLDS16(gBp[1] + ko_, lb_ + 8192 + ldsoB[1]);                     \
  } while (0)
#define COMPUTE(BUF) do {                                            \
    const half8* AsV = (const half8*)(LDSBUF(BUF));                  \
    const half8* BsV = (const half8*)(LDSBUF(BUF) + 8192);           \
    half8 a_[4], b_[4];                                              \
    _Pragma("unroll")                                                \
    for (int i = 0; i < 4; ++i) a_[i] = AsV[aoff[i]];                \
    _Pragma("unroll")                                                \
    for (int i = 0; i < 4; ++i) b_[i] = BsV[boff[i]];                \
    _Pragma("unroll")                                                \
    for (int mi = 0; mi < 4; ++mi)                                   \
      _Pragma("unroll")                                              \
      for (int ni = 0; ni < 4; ++ni)                                 \
        acc[mi][ni] = __builtin_amdgcn_mfma_f32_16x16x32_f16(a_[mi], b_[ni], acc[mi][ni], 0, 0, 0); \
  } while (0)

  STAGE(0, 0);                         // prologue: fill 2 buffers (8 loads in flight)
  STAGE(1, 1);

#pragma unroll 1
  for (int kt = 0; kt < NKIT - 2; kt += 3) {
    __builtin_amdgcn_s_waitcnt(WAITCNT_VM4);
    __builtin_amdgcn_s_barrier();
    __asm__ volatile("" ::: "memory");
    STAGE(kt + 2, 2);
    COMPUTE(0);
    __builtin_amdgcn_s_waitcnt(WAITCNT_VM4);
    __builtin_amdgcn_s_barrier();
    __asm__ volatile("" ::: "memory");
    STAGE(kt + 3, 0);
    COMPUTE(1);
    __builtin_amdgcn_s_waitcnt(WAITCNT_VM4);
    __builtin_amdgcn_s_barrier();
    __asm__ volatile("" ::: "memory");
    STAGE(kt + 4, 1);
    COMPUTE(2);
  }
  __builtin_amdgcn_s_waitcnt(WAITCNT_VM4);
  __builtin_amdgcn_s_barrier();
  __asm__ volatile("" ::: "memory");
  COMPUTE(0);
  __builtin_amdgcn_s_waitcnt(WAITCNT_VM0);
  __builtin_amdgcn_s_barrier();
  __asm__ volatile("" ::: "memory");
  COMPUTE(1);
#undef COMPUTE
#undef STAGE
#undef LDSBUF

  // epilogue. C/D layout: col = lane&15, row = quad*4 + reg
  const float* bptr = bias + (size_t)eid * DD;
#pragma unroll
  for (int mi = 0; mi < 4; ++mi) {
    int rowb = m0 + wm * 64 + mi * 16 + quad * 4;
#pragma unroll
    for (int rr = 0; rr < 4; ++rr) {
      int gpos = rowb + rr;
      if (gpos < seg_end) {
        if (MODE == 0) {
#pragma unroll
          for (int ni = 0; ni < 4; ++ni) {
            int n = n0 + wq * 64 + ni * 16 + r15;
            float val = acc[mi][ni][rr] + bptr[n];
            val = 0.5f * val * (1.0f + erff(val * 0.70710678118654752f));
            Hout[(size_t)gpos * DD + n] = (_Float16)val;
          }
        } else {
          int tok = rowtok_lds[gpos - m0];
          float wgl = wgt[tok];
          float* orow = Fout + (size_t)tok * DD;
#pragma unroll
          for (int ni = 0; ni < 4; ++ni) {
            int n = n0 + wq * 64 + ni * 16 + r15;
            orow[n] = (acc[mi][ni][rr] + bptr[n]) * wgl;
          }
        }
      }
    }
  }
}

extern "C" void kernel_launch(void* const* d_in, const int* in_sizes, int n_in,
                              void* d_out, int out_size, void* d_ws, size_t ws_size,
                              hipStream_t stream) {
  const float* x  = (const float*)d_in[0];
  const float* Wg = (const float*)d_in[1];
  const float* bg = (const float*)d_in[2];
  const float* W1 = (const float*)d_in[3];
  const float* b1 = (const float*)d_in[4];
  const float* W2 = (const float*)d_in[5];
  const float* b2 = (const float*)d_in[6];
  float* out = (float*)d_out;

  char* ws = (char*)d_ws;
  const size_t MB16 = (size_t)1 << 24;
  _Float16* W1t = (_Float16*)(ws + 0 * MB16);
  _Float16* W2t = (_Float16*)(ws + 1 * MB16);
  _Float16* xh  = (_Float16*)(ws + 2 * MB16);
  _Float16* H   = (_Float16*)(ws + 3 * MB16);
  int*   assign = (int*)(ws + 4 * MB16);
  float* wgt    = (float*)(assign + NT);

  prep_kernel<<<4096 + NT / 8, 256, 0, stream>>>(W1, W2, W1t, W2t, x, Wg, bg, assign, wgt, xh);
  gemm_kernel<0><<<MAXTILE * 8, 256, 0, stream>>>(xh, W1t, b1, assign, H, nullptr, wgt);
  gemm_kernel<1><<<MAXTILE * 8, 256, 0, stream>>>(H, W2t, b2, assign, nullptr, out, wgt);
}

// Round 13
// 264.572 us; speedup vs baseline: 2.8777x; 1.0284x over previous
//
#include <hip/hip_runtime.h>
#include <cstdint>

#define NT 8192
#define DD 1024
#define NE 8
#define BK 32
#define NKIT (DD / BK)
#define TM 128                 // m-tile
#define MAXTILE 72             // sum ceil(c/128) <= 8192/128 + 8
#define TPX (MAXTILE / 8)      // tiles per XCD = 9

typedef __attribute__((ext_vector_type(8))) _Float16 half8;
typedef __attribute__((ext_vector_type(4))) float f32x4;

__device__ __forceinline__ unsigned short f2h_bits(float f) {
  _Float16 h = (_Float16)f;
  return __builtin_bit_cast(unsigned short, h);
}

// async global->LDS, 16B per lane. LDS dest must be wave-uniform base + lane*16;
// the GLOBAL address is an ordinary per-lane VGPR address (indirection is fine).
#define GLDS16(gp, lp) __builtin_amdgcn_global_load_lds( \
  (__attribute__((address_space(1))) void*)(uintptr_t)(gp), \
  (__attribute__((address_space(3))) void*)(uintptr_t)(lp), 16, 0, 0)

// s_waitcnt imm (gfx9): vmcnt[3:0]|[15:14], expcnt[6:4], lgkmcnt[11:8]; 0xF70|N = vmcnt(N) only
#define WAITCNT_VM4  0xF74
#define WAITCNT_VM0  0xF70

// ---------------- fused prep: wcast (blocks 0..4095) + gate (blocks 4096..5119) ----------------
__global__ __launch_bounds__(256) void prep_kernel(
    const float* __restrict__ W1, const float* __restrict__ W2,
    _Float16* __restrict__ W1t, _Float16* __restrict__ W2t,
    const float* __restrict__ x, const float* __restrict__ Wg, const float* __restrict__ bg,
    int* __restrict__ assign, float* __restrict__ wgt, _Float16* __restrict__ xh) {
  __shared__ alignas(16) char smem[32768];
  const int bid = blockIdx.x;
  const int tid = threadIdx.x;
  if (bid < 4096) {
    // ---- wcast path: fp32 [e][k][n] -> fp16 [e][n][k] ----
    float (*tile)[65] = (float (*)[65])smem;   // 64 x 65 floats = 16.6 KB
    const int z = bid >> 8;                    // 0..15: [0,8)=W1, [8,16)=W2
    const float* W = (z < 8 ? W1 : W2) + (size_t)(z & 7) * (DD * DD);
    _Float16* Wt   = (z < 8 ? W1t : W2t) + (size_t)(z & 7) * (DD * DD);
    const int k0 = (bid & 15) * 64, n0 = ((bid >> 4) & 15) * 64;
#pragma unroll
    for (int it = 0; it < 4; ++it) {
      int idx = it * 256 + tid;                // 0..1023
      int r = idx >> 4;                        // k-row 0..63
      int q = idx & 15;                        // float4 col
      float4 v = *(const float4*)(W + (size_t)(k0 + r) * DD + n0 + q * 4);
      tile[r][q * 4 + 0] = v.x; tile[r][q * 4 + 1] = v.y;
      tile[r][q * 4 + 2] = v.z; tile[r][q * 4 + 3] = v.w;
    }
    __syncthreads();
#pragma unroll
    for (int it = 0; it < 4; ++it) {
      int idx = it * 256 + tid;
      int n = idx >> 4;                        // out row (n) 0..63
      int q = idx & 15;                        // k 4-chunk
      ushort4 o;
      o.x = f2h_bits(tile[q * 4 + 0][n]);
      o.y = f2h_bits(tile[q * 4 + 1][n]);
      o.z = f2h_bits(tile[q * 4 + 2][n]);
      o.w = f2h_bits(tile[q * 4 + 3][n]);
      *(ushort4*)(Wt + (size_t)(n0 + n) * DD + k0 + q * 4) = o;
    }
  } else {
    // ---- gate path ----
    float* WgL = (float*)smem;                 // NE*DD floats = 32 KB, e-major
    const int gb = bid - 4096;                 // 0..1023
#pragma unroll
    for (int it = 0; it < 8; ++it) {
      int idx = it * 256 + tid;                // float4 index 0..2047
      float4 v = ((const float4*)Wg)[idx];
      int k = idx >> 1;
      int e0 = (idx & 1) * 4;
      WgL[(e0 + 0) * DD + k] = v.x;
      WgL[(e0 + 1) * DD + k] = v.y;
      WgL[(e0 + 2) * DD + k] = v.z;
      WgL[(e0 + 3) * DD + k] = v.w;
    }
    __syncthreads();
    const int lane = tid & 63, w = tid >> 6;
#pragma unroll
    for (int s = 0; s < 2; ++s) {
      const int t = gb * 8 + w * 2 + s;
      const float4* xr = (const float4*)(x + (size_t)t * DD);
      float4 xv[4];
#pragma unroll
      for (int c = 0; c < 4; ++c) xv[c] = xr[lane + 64 * c];
      ushort4* xo = (ushort4*)(xh + (size_t)t * DD);
#pragma unroll
      for (int c = 0; c < 4; ++c) {
        union { ushort4 u; _Float16 h[4]; } cv;
        cv.h[0] = (_Float16)xv[c].x; cv.h[1] = (_Float16)xv[c].y;
        cv.h[2] = (_Float16)xv[c].z; cv.h[3] = (_Float16)xv[c].w;
        xo[lane + 64 * c] = cv.u;
      }
      float p[NE];
#pragma unroll
      for (int e = 0; e < NE; ++e) {
        float acc = 0.f;
#pragma unroll
        for (int c = 0; c < 4; ++c) {
          float4 wv = *(const float4*)&WgL[e * DD + 4 * lane + 256 * c];
          acc += xv[c].x * wv.x + xv[c].y * wv.y + xv[c].z * wv.z + xv[c].w * wv.w;
        }
        p[e] = acc;
      }
#pragma unroll
      for (int e = 0; e < NE; ++e) {
        float v = p[e];
        for (int off = 32; off > 0; off >>= 1) v += __shfl_down(v, off, 64);
        p[e] = v;
      }
      if (lane == 0) {
        float l[NE];
#pragma unroll
        for (int e = 0; e < NE; ++e) l[e] = p[e] + bg[e];
        int a = 0; float best = l[0];
#pragma unroll
        for (int e = 1; e < NE; ++e) if (l[e] > best) { best = l[e]; a = e; }
        float sum = 0.f;
#pragma unroll
        for (int e = 0; e < NE; ++e) sum += expf(l[e] - best);
        assign[t] = a;
        wgt[t] = 1.0f / sum;
      }
    }
  }
}

// ---------------- sort: shuffle-scan counting sort + tile plan (R9 version, one block) ----------------
__global__ __launch_bounds__(1024) void sort_kernel(
    const int* __restrict__ assign, int* __restrict__ rowtok, int* __restrict__ plan) {
  __shared__ int wsum[16][NE];
  __shared__ int wbase[16][NE];
  __shared__ int s_offs[NE];
  __shared__ int s_tot[NE];
  __shared__ int s_pref[NE + 1];
  const int tid = threadIdx.x;
  const int lane = tid & 63, wv = tid >> 6;   // 16 waves
  int a[8];
  int c[NE];
#pragma unroll
  for (int e = 0; e < NE; ++e) c[e] = 0;
#pragma unroll
  for (int j = 0; j < 8; ++j) { a[j] = assign[tid * 8 + j]; ++c[a[j]]; }
  int inc[NE];
#pragma unroll
  for (int e = 0; e < NE; ++e) inc[e] = c[e];
  for (int d = 1; d < 64; d <<= 1) {
#pragma unroll
    for (int e = 0; e < NE; ++e) {
      int u = __shfl_up(inc[e], d, 64);
      if (lane >= d) inc[e] += u;
    }
  }
  if (lane == 63) {
#pragma unroll
    for (int e = 0; e < NE; ++e) wsum[wv][e] = inc[e];
  }
  __syncthreads();
  if (wv == 0 && lane < 16) {
    int v[NE], incw[NE];
#pragma unroll
    for (int e = 0; e < NE; ++e) { v[e] = wsum[lane][e]; incw[e] = v[e]; }
    for (int d = 1; d < 16; d <<= 1) {
#pragma unroll
      for (int e = 0; e < NE; ++e) {
        int u = __shfl_up(incw[e], d, 64);
        if (lane >= d) incw[e] += u;
      }
    }
    int tote[NE];
#pragma unroll
    for (int e = 0; e < NE; ++e) tote[e] = __shfl(incw[e], 15, 64);
    int offs[NE];
    {
      int s = 0;
#pragma unroll
      for (int e = 0; e < NE; ++e) { offs[e] = s; s += tote[e]; }
    }
#pragma unroll
    for (int e = 0; e < NE; ++e) wbase[lane][e] = offs[e] + incw[e] - v[e];
    if (lane == 0) {
      int s = 0;
#pragma unroll
      for (int e = 0; e < NE; ++e) {
        s_offs[e] = offs[e]; s_tot[e] = tote[e];
        s_pref[e] = s; s += (tote[e] + TM - 1) / TM;
      }
      s_pref[NE] = s;
      plan[0] = s;
    }
  }
  __syncthreads();
  int run[NE];
#pragma unroll
  for (int e = 0; e < NE; ++e) run[e] = wbase[wv][e] + inc[e] - c[e];
#pragma unroll
  for (int j = 0; j < 8; ++j) { int e = a[j]; rowtok[run[e]++] = tid * 8 + j; }
  const int nt = s_pref[NE];
  if (tid < nt) {
    int e = 0;
    while (tid >= s_pref[e + 1]) ++e;
    int t = tid - s_pref[e];
    plan[1 + tid] = e;
    plan[1 + MAXTILE + tid] = s_offs[e] + t * TM;
    plan[1 + 2 * MAXTILE + tid] = s_offs[e] + s_tot[e];
  }
}

// ---------------- gemm body: R5's proven 128x128 / 4-wave / 3-buffer pipeline ----------------
// MODE 0: H[p] = gelu_exact(xh[rowtok[p]] @ W1t^T + b1)  -> fp16
// MODE 1: out[rowtok[p]] = (H[p] @ W2t^T + b2) * wgt      -> fp32 scatter
// NOTE: H is intentionally NOT __restrict__ anywhere in the fused kernel (written as Hout in
// phase 0, read as A in phase 1 of the same kernel).
template <int MODE>
__device__ void gemm_body(
    const _Float16* A, const _Float16* Wt, const float* bias,
    _Float16* Hout, float* Fout,
    const int* rowtok, const float* wgt, char* lds,
    int e, int m0, int seg_end, int n0) {
  const int tid = threadIdx.x;
  const int lane = tid & 63;
  const int wv = tid >> 6;             // wave 0..3
  const int wm = wv >> 1;              // m half 0..1 (64 rows)
  const int wq = wv & 1;               // n half 0..1 (64 cols)
  const int quad = lane >> 4;
  const int r15 = lane & 15;

  const _Float16* We = Wt + (size_t)e * DD * DD;
  const _Float16* gAp[2];
  const _Float16* gBp[2];
  int ldsoA[2], ldsoB[2];
#pragma unroll
  for (int i = 0; i < 2; ++i) {
    int slot = i * 256 + tid;
    int row = slot >> 2;               // 0..127
    int c = (slot & 3) ^ ((row >> 1) & 3);
    int rg = m0 + row; if (rg > NT - 1) rg = NT - 1;
    int arow = (MODE == 0) ? rowtok[rg] : rg;
    gAp[i] = A + (size_t)arow * DD + c * 8;
    ldsoA[i] = slot * 16;
    gBp[i] = We + (size_t)(n0 + row) * DD + c * 8;
    ldsoB[i] = slot * 16;
  }

  int aoff[4], boff[4];
#pragma unroll
  for (int i = 0; i < 4; ++i) {
    int m = wm * 64 + i * 16 + r15;
    aoff[i] = m * 4 + (quad ^ ((m >> 1) & 3));
    int n = wq * 64 + i * 16 + r15;
    boff[i] = n * 4 + (quad ^ ((n >> 1) & 3));
  }

  f32x4 acc[4][4];
  f32x4 zero4 = {0.f, 0.f, 0.f, 0.f};
#pragma unroll
  for (int mi = 0; mi < 4; ++mi)
#pragma unroll
    for (int ni = 0; ni < 4; ++ni) acc[mi][ni] = zero4;

#define LDSBUF(B) (lds + (B) * 16384)
#define STAGE(KT, BUF) do {                                          \
    const int ko_ = (KT) * BK;                                       \
    char* lb_ = LDSBUF(BUF);                                         \
    GLDS16(gAp[0] + ko_, lb_ + ldsoA[0]);                            \
    GLDS16(gAp[1] + ko_, lb_ + ldsoA[1]);                            \
    GLDS16(gBp[0] + ko_, lb_ + 8192 + ldsoB[0]);                     \
    GLDS16(gBp[1] + ko_, lb_ + 8192 + ldsoB[1]);                     \
  } while (0)
#define COMPUTE(BUF) do {                                            \
    const half8* AsV = (const half8*)(LDSBUF(BUF));                  \
    const half8* BsV = (const half8*)(LDSBUF(BUF) + 8192);           \
    half8 a_[4], b_[4];                                              \
    _Pragma("unroll")                                                \
    for (int i = 0; i < 4; ++i) a_[i] = AsV[aoff[i]];                \
    _Pragma("unroll")                                                \
    for (int i = 0; i < 4; ++i) b_[i] = BsV[boff[i]];                \
    _Pragma("unroll")                                                \
    for (int mi = 0; mi < 4; ++mi)                                   \
      _Pragma("unroll")                                              \
      for (int ni = 0; ni < 4; ++ni)                                 \
        acc[mi][ni] = __builtin_amdgcn_mfma_f32_16x16x32_f16(a_[mi], b_[ni], acc[mi][ni], 0, 0, 0); \
  } while (0)

  STAGE(0, 0);
  STAGE(1, 1);

#pragma unroll 1
  for (int kt = 0; kt < NKIT - 2; kt += 3) {
    __builtin_amdgcn_s_waitcnt(WAITCNT_VM4);
    __builtin_amdgcn_s_barrier();
    __asm__ volatile("" ::: "memory");
    STAGE(kt + 2, 2);
    COMPUTE(0);
    __builtin_amdgcn_s_waitcnt(WAITCNT_VM4);
    __builtin_amdgcn_s_barrier();
    __asm__ volatile("" ::: "memory");
    STAGE(kt + 3, 0);
    COMPUTE(1);
    __builtin_amdgcn_s_waitcnt(WAITCNT_VM4);
    __builtin_amdgcn_s_barrier();
    __asm__ volatile("" ::: "memory");
    STAGE(kt + 4, 1);
    COMPUTE(2);
  }
  __builtin_amdgcn_s_waitcnt(WAITCNT_VM4);
  __builtin_amdgcn_s_barrier();
  __asm__ volatile("" ::: "memory");
  COMPUTE(0);
  __builtin_amdgcn_s_waitcnt(WAITCNT_VM0);
  __builtin_amdgcn_s_barrier();
  __asm__ volatile("" ::: "memory");
  COMPUTE(1);
#undef COMPUTE
#undef STAGE
#undef LDSBUF

  const float* bptr = bias + (size_t)e * DD;
#pragma unroll
  for (int mi = 0; mi < 4; ++mi) {
    int rowb = m0 + wm * 64 + mi * 16 + quad * 4;
#pragma unroll
    for (int rr = 0; rr < 4; ++rr) {
      int gpos = rowb + rr;
      if (gpos < seg_end) {
        if (MODE == 0) {
#pragma unroll
          for (int ni = 0; ni < 4; ++ni) {
            int n = n0 + wq * 64 + ni * 16 + r15;
            float val = acc[mi][ni][rr] + bptr[n];
            val = 0.5f * val * (1.0f + erff(val * 0.70710678118654752f));
            Hout[(size_t)gpos * DD + n] = (_Float16)val;
          }
        } else {
          int tok = rowtok[gpos];
          float wgl = wgt[tok];
          float* orow = Fout + (size_t)tok * DD;
#pragma unroll
          for (int ni = 0; ni < 4; ++ni) {
            int n = n0 + wq * 64 + ni * 16 + r15;
            orow[n] = (acc[mi][ni][rr] + bptr[n]) * wgl;
          }
        }
      }
    }
  }
}

// ---------------- fused gemm0+gemm1: per-tile producer-consumer, no grid barrier ----------------
// R12 post-mortem: replicated in-block sort = scratch-indexed register arrays (rule #20),
// +47us/dispatch -> revert to 1-block sort kernel. R11 taught: harness overhead ~110us is
// FIXED per bench (fused 638us kernel still showed total-kernel = 123us), so only device time
// matters. Remaining waste: 576 blocks on 256 CUs = 2.25/CU -> 3-block CUs set each gemm's
// makespan (~25% tail idle) AND gemm1 waits for ALL of gemm0. Fix both: one kernel; block
// (tile,nb) computes H panel, release-adds flag[tile] (agent scope: wbl2 makes H visible
// device-wide regardless of XCD mapping), then tid0 spins (s_sleep) until flag[tile]==8,
// then computes its gemm1 item. All 576 blocks co-resident (<=768 by 48KB LDS + lb(256,3))
// -> tile-mates always progress -> no deadlock. __syncthreads before the release drains
// every wave's H stores (compiler emits vmcnt(0) before s_barrier).
__global__ __launch_bounds__(256, 3) void gemm_fused(
    const _Float16* __restrict__ xh,
    const _Float16* __restrict__ W1t, const float* __restrict__ b1,
    _Float16* H,                      // NOT restrict: written phase 0, read phase 1
    const _Float16* __restrict__ W2t, const float* __restrict__ b2,
    float* __restrict__ out,
    const int* __restrict__ plan, const int* __restrict__ rowtok,
    const float* __restrict__ wgt, unsigned* __restrict__ flags) {
  __shared__ alignas(16) char lds[49152];
  const int wrk = blockIdx.x;
  const int g = wrk & 7;               // XCD-aware bijection (bid%8 round-robin)
  const int r = wrk >> 3;              // 0..71
  const int tile = g * TPX + (r >> 3);
  const int nb = r & 7;
  if (tile >= plan[0]) return;         // block-uniform exit; no consumer waits on this tile
  const int e = plan[1 + tile];
  const int m0 = plan[1 + MAXTILE + tile];
  const int seg_end = plan[1 + 2 * MAXTILE + tile];
  const int n0 = nb * 128;

  // ---- phase 0: produce H panel ----
  gemm_body<0>(xh, W1t, b1, H, nullptr, rowtok, nullptr, lds, e, m0, seg_end, n0);

  __syncthreads();                     // drains all waves' vmcnt -> H stores in L2
  if (threadIdx.x == 0)
    __hip_atomic_fetch_add(&flags[tile], 1u, __ATOMIC_RELEASE, __HIP_MEMORY_SCOPE_AGENT);

  // ---- wait for the 7 tile-mates (co-resident; same XCD under the swizzle) ----
  if (threadIdx.x == 0) {
    while (__hip_atomic_load(&flags[tile], __ATOMIC_ACQUIRE, __HIP_MEMORY_SCOPE_AGENT) < 8u)
      __builtin_amdgcn_s_sleep(2);
  }
  __syncthreads();                     // all waves see acquired state; LDS free for phase 1

  // ---- phase 1: consume H tile, produce output ----
  gemm_body<1>(H, W2t, b2, nullptr, out, rowtok, wgt, lds, e, m0, seg_end, n0);
}

extern "C" void kernel_launch(void* const* d_in, const int* in_sizes, int n_in,
                              void* d_out, int out_size, void* d_ws, size_t ws_size,
                              hipStream_t stream) {
  const float* x  = (const float*)d_in[0];
  const float* Wg = (const float*)d_in[1];
  const float* bg = (const float*)d_in[2];
  const float* W1 = (const float*)d_in[3];
  const float* b1 = (const float*)d_in[4];
  const float* W2 = (const float*)d_in[5];
  const float* b2 = (const float*)d_in[6];
  float* out = (float*)d_out;

  char* ws = (char*)d_ws;
  const size_t MB16 = (size_t)1 << 24;
  _Float16* W1t = (_Float16*)(ws + 0 * MB16);
  _Float16* W2t = (_Float16*)(ws + 1 * MB16);
  _Float16* xh  = (_Float16*)(ws + 2 * MB16);
  _Float16* H   = (_Float16*)(ws + 3 * MB16);
  int*   assign = (int*)(ws + 4 * MB16);
  int*   rowtok = assign + NT;
  float* wgt    = (float*)(rowtok + NT);
  int*   plan   = (int*)(wgt + NT);    // [1 + 3*MAXTILE]
  unsigned* flags = (unsigned*)(plan + 512);   // [MAXTILE], zeroed per launch

  hipMemsetAsync(flags, 0, MAXTILE * sizeof(unsigned), stream);
  prep_kernel<<<4096 + NT / 8, 256, 0, stream>>>(W1, W2, W1t, W2t, x, Wg, bg, assign, wgt, xh);
  sort_kernel<<<1, 1024, 0, stream>>>(assign, rowtok, plan);
  gemm_fused<<<MAXTILE * 8, 256, 0, stream>>>(xh, W1t, b1, H, W2t, b2, out,
                                              plan, rowtok, wgt, flags);
}

// Round 14
// 229.210 us; speedup vs baseline: 3.3216x; 1.1543x over previous
//
#include <hip/hip_runtime.h>
#include <cstdint>

#define NT 8192
#define DD 1024
#define NE 8
#define BK 32
#define NKIT (DD / BK)
#define TM 128                 // m-tile
#define MAXTILE 72             // sum ceil(c/128) <= 8192/128 + 8
#define TPX (MAXTILE / 8)      // tiles per XCD = 9

typedef __attribute__((ext_vector_type(8))) _Float16 half8;
typedef __attribute__((ext_vector_type(4))) float f32x4;

__device__ __forceinline__ unsigned short f2h_bits(float f) {
  _Float16 h = (_Float16)f;
  return __builtin_bit_cast(unsigned short, h);
}

// async global->LDS, 16B per lane. LDS dest must be wave-uniform base + lane*16;
// the GLOBAL address is an ordinary per-lane VGPR address (indirection is fine).
#define GLDS16(gp, lp) __builtin_amdgcn_global_load_lds( \
  (__attribute__((address_space(1))) void*)(uintptr_t)(gp), \
  (__attribute__((address_space(3))) void*)(uintptr_t)(lp), 16, 0, 0)

// s_waitcnt imm (gfx9): vmcnt[3:0]|[15:14], expcnt[6:4], lgkmcnt[11:8]; 0xF70|N = vmcnt(N) only
#define WAITCNT_VM4  0xF74
#define WAITCNT_VM0  0xF70

// ---------------- fused prep: wcast (blocks 0..4095) + gate (blocks 4096..5119) ----------------
__global__ __launch_bounds__(256) void prep_kernel(
    const float* __restrict__ W1, const float* __restrict__ W2,
    _Float16* __restrict__ W1t, _Float16* __restrict__ W2t,
    const float* __restrict__ x, const float* __restrict__ Wg, const float* __restrict__ bg,
    int* __restrict__ assign, float* __restrict__ wgt, _Float16* __restrict__ xh) {
  __shared__ alignas(16) char smem[32768];
  const int bid = blockIdx.x;
  const int tid = threadIdx.x;
  if (bid < 4096) {
    // ---- wcast path: fp32 [e][k][n] -> fp16 [e][n][k] ----
    float (*tile)[65] = (float (*)[65])smem;   // 64 x 65 floats = 16.6 KB
    const int z = bid >> 8;                    // 0..15: [0,8)=W1, [8,16)=W2
    const float* W = (z < 8 ? W1 : W2) + (size_t)(z & 7) * (DD * DD);
    _Float16* Wt   = (z < 8 ? W1t : W2t) + (size_t)(z & 7) * (DD * DD);
    const int k0 = (bid & 15) * 64, n0 = ((bid >> 4) & 15) * 64;
#pragma unroll
    for (int it = 0; it < 4; ++it) {
      int idx = it * 256 + tid;                // 0..1023
      int r = idx >> 4;                        // k-row 0..63
      int q = idx & 15;                        // float4 col
      float4 v = *(const float4*)(W + (size_t)(k0 + r) * DD + n0 + q * 4);
      tile[r][q * 4 + 0] = v.x; tile[r][q * 4 + 1] = v.y;
      tile[r][q * 4 + 2] = v.z; tile[r][q * 4 + 3] = v.w;
    }
    __syncthreads();
#pragma unroll
    for (int it = 0; it < 4; ++it) {
      int idx = it * 256 + tid;
      int n = idx >> 4;                        // out row (n) 0..63
      int q = idx & 15;                        // k 4-chunk
      ushort4 o;
      o.x = f2h_bits(tile[q * 4 + 0][n]);
      o.y = f2h_bits(tile[q * 4 + 1][n]);
      o.z = f2h_bits(tile[q * 4 + 2][n]);
      o.w = f2h_bits(tile[q * 4 + 3][n]);
      *(ushort4*)(Wt + (size_t)(n0 + n) * DD + k0 + q * 4) = o;
    }
  } else {
    // ---- gate path ----
    float* WgL = (float*)smem;                 // NE*DD floats = 32 KB, e-major
    const int gb = bid - 4096;                 // 0..1023
#pragma unroll
    for (int it = 0; it < 8; ++it) {
      int idx = it * 256 + tid;                // float4 index 0..2047
      float4 v = ((const float4*)Wg)[idx];
      int k = idx >> 1;
      int e0 = (idx & 1) * 4;
      WgL[(e0 + 0) * DD + k] = v.x;
      WgL[(e0 + 1) * DD + k] = v.y;
      WgL[(e0 + 2) * DD + k] = v.z;
      WgL[(e0 + 3) * DD + k] = v.w;
    }
    __syncthreads();
    const int lane = tid & 63, w = tid >> 6;
#pragma unroll
    for (int s = 0; s < 2; ++s) {
      const int t = gb * 8 + w * 2 + s;
      const float4* xr = (const float4*)(x + (size_t)t * DD);
      float4 xv[4];
#pragma unroll
      for (int c = 0; c < 4; ++c) xv[c] = xr[lane + 64 * c];
      ushort4* xo = (ushort4*)(xh + (size_t)t * DD);
#pragma unroll
      for (int c = 0; c < 4; ++c) {
        union { ushort4 u; _Float16 h[4]; } cv;
        cv.h[0] = (_Float16)xv[c].x; cv.h[1] = (_Float16)xv[c].y;
        cv.h[2] = (_Float16)xv[c].z; cv.h[3] = (_Float16)xv[c].w;
        xo[lane + 64 * c] = cv.u;
      }
      float p[NE];
#pragma unroll
      for (int e = 0; e < NE; ++e) {
        float acc = 0.f;
#pragma unroll
        for (int c = 0; c < 4; ++c) {
          float4 wv = *(const float4*)&WgL[e * DD + 4 * lane + 256 * c];
          acc += xv[c].x * wv.x + xv[c].y * wv.y + xv[c].z * wv.z + xv[c].w * wv.w;
        }
        p[e] = acc;
      }
#pragma unroll
      for (int e = 0; e < NE; ++e) {
        float v = p[e];
        for (int off = 32; off > 0; off >>= 1) v += __shfl_down(v, off, 64);
        p[e] = v;
      }
      if (lane == 0) {
        float l[NE];
#pragma unroll
        for (int e = 0; e < NE; ++e) l[e] = p[e] + bg[e];
        int a = 0; float best = l[0];
#pragma unroll
        for (int e = 1; e < NE; ++e) if (l[e] > best) { best = l[e]; a = e; }
        float sum = 0.f;
#pragma unroll
        for (int e = 0; e < NE; ++e) sum += expf(l[e] - best);
        assign[t] = a;
        wgt[t] = 1.0f / sum;
      }
    }
  }
}

// ---------------- sort: shuffle-scan counting sort + tile plan (128-row tiles) ----------------
// Per-wave register scan via __shfl_up (6 steps, no LDS), 16 wave-totals scanned by wave 0,
// 2 barriers total. Deterministic token order (global exclusive prefix per expert).
__global__ __launch_bounds__(1024) void sort_kernel(
    const int* __restrict__ assign, int* __restrict__ rowtok, int* __restrict__ plan) {
  __shared__ int wsum[16][NE];
  __shared__ int wbase[16][NE];
  __shared__ int s_offs[NE];
  __shared__ int s_tot[NE];
  __shared__ int s_pref[NE + 1];
  const int tid = threadIdx.x;
  const int lane = tid & 63, wv = tid >> 6;   // 16 waves
  int a[8];
  int c[NE];
#pragma unroll
  for (int e = 0; e < NE; ++e) c[e] = 0;
#pragma unroll
  for (int j = 0; j < 8; ++j) { a[j] = assign[tid * 8 + j]; ++c[a[j]]; }
  int inc[NE];
#pragma unroll
  for (int e = 0; e < NE; ++e) inc[e] = c[e];
  for (int d = 1; d < 64; d <<= 1) {
#pragma unroll
    for (int e = 0; e < NE; ++e) {
      int u = __shfl_up(inc[e], d, 64);
      if (lane >= d) inc[e] += u;
    }
  }
  if (lane == 63) {
#pragma unroll
    for (int e = 0; e < NE; ++e) wsum[wv][e] = inc[e];
  }
  __syncthreads();
  if (wv == 0 && lane < 16) {
    int v[NE], incw[NE];
#pragma unroll
    for (int e = 0; e < NE; ++e) { v[e] = wsum[lane][e]; incw[e] = v[e]; }
    for (int d = 1; d < 16; d <<= 1) {
#pragma unroll
      for (int e = 0; e < NE; ++e) {
        int u = __shfl_up(incw[e], d, 64);
        if (lane >= d) incw[e] += u;
      }
    }
    int tote[NE];
#pragma unroll
    for (int e = 0; e < NE; ++e) tote[e] = __shfl(incw[e], 15, 64);
    int offs[NE];
    {
      int s = 0;
#pragma unroll
      for (int e = 0; e < NE; ++e) { offs[e] = s; s += tote[e]; }
    }
#pragma unroll
    for (int e = 0; e < NE; ++e) wbase[lane][e] = offs[e] + incw[e] - v[e];
    if (lane == 0) {
      int s = 0;
#pragma unroll
      for (int e = 0; e < NE; ++e) {
        s_offs[e] = offs[e]; s_tot[e] = tote[e];
        s_pref[e] = s; s += (tote[e] + TM - 1) / TM;
      }
      s_pref[NE] = s;
      plan[0] = s;
    }
  }
  __syncthreads();
  int run[NE];
#pragma unroll
  for (int e = 0; e < NE; ++e) run[e] = wbase[wv][e] + inc[e] - c[e];
#pragma unroll
  for (int j = 0; j < 8; ++j) { int e = a[j]; rowtok[run[e]++] = tid * 8 + j; }
  const int nt = s_pref[NE];
  if (tid < nt) {
    int e = 0;
    while (tid >= s_pref[e + 1]) ++e;
    int t = tid - s_pref[e];
    plan[1 + tid] = e;
    plan[1 + MAXTILE + tid] = s_offs[e] + t * TM;
    plan[1 + 2 * MAXTILE + tid] = s_offs[e] + s_tot[e];
  }
}

// ---------------- grouped GEMM: 128x128 tile, 4 waves (64x64 each), 3-buffer depth-2 ----------------
// Session optimum (R5/R9 config, 46-48us/dispatch, FETCH 22MB via XCD swizzle). Structural
// plateau evidence: 8 variants (waves 4/8, tiles 64^2-256^2, BK 32/64, depth 1-3, occupancy
// 11-55%) all 46-55us; our 354 TF at K=1024 is ABOVE the m97-structure reference curve (m102:
// 90/320/833 TF at K=1024/2048/4096) for this K. Faster structures (256^2 8-phase) need >=256
// filled 256^2 blocks; this problem supplies 160 (refuted R8). Fusion variants all negative
// (R11 software grid barrier ~160us each; R12 replicated sort scratch-bound; R13 per-tile
// flags destroy H L2 reuse). Harness-fixed overhead ~106us is kernel-count-invariant.
// MODE 0: H[p] = gelu_exact(xh[rowtok[p]] @ W1t^T + b1)  -> fp16
// MODE 1: out[rowtok[p]] = (H[p] @ W2t^T + b2) * wgt      -> fp32 scatter
template <int MODE>
__global__ __launch_bounds__(256, 3) void gemm_kernel(
    const _Float16* __restrict__ A,
    const _Float16* __restrict__ Wt,
    const float* __restrict__ bias,
    const int* __restrict__ plan,
    _Float16* __restrict__ Hout,
    float* __restrict__ Fout,
    const int* __restrict__ rowtok,
    const float* __restrict__ wgt) {
  const int wrk = blockIdx.x;
  // XCD-aware bijection: g = XCD (bid%8 round-robin), r = rank within XCD.
  const int g = wrk & 7;
  const int r = wrk >> 3;             // 0..71
  const int tile = g * TPX + (r >> 3);
  const int nb = r & 7;
  if (tile >= plan[0]) return;
  const int e = plan[1 + tile];
  const int m0 = plan[1 + MAXTILE + tile];
  const int seg_end = plan[1 + 2 * MAXTILE + tile];
  const int n0 = nb * 128;

  const int tid = threadIdx.x;
  const int lane = tid & 63;
  const int wv = tid >> 6;             // wave 0..3
  const int wm = wv >> 1;              // m half 0..1 (64 rows)
  const int wq = wv & 1;               // n half 0..1 (64 cols)
  const int quad = lane >> 4;
  const int r15 = lane & 15;

  // LDS: 3 buffers x (A 8KB + B 8KB) = 48 KB -> 3 blocks/CU
  __shared__ alignas(16) char lds[49152];

  // staging: A-tile 128 rows x 32 halves (8 KB) = 512 slots of 16B over 256 threads
  // (2 slots/thread: tid, tid+256). Same for B. slot -> row = slot>>2, stored chunk
  // sc = slot&3, logical chunk c = sc ^ ((row>>1)&3)  (chunk = 8 halves = 16B).
  const _Float16* We = Wt + (size_t)e * DD * DD;
  const _Float16* gAp[2];
  const _Float16* gBp[2];
  int ldsoA[2], ldsoB[2];
#pragma unroll
  for (int i = 0; i < 2; ++i) {
    int slot = i * 256 + tid;
    int row = slot >> 2;               // 0..127
    int c = (slot & 3) ^ ((row >> 1) & 3);
    int rg = m0 + row; if (rg > NT - 1) rg = NT - 1;
    int arow = (MODE == 0) ? rowtok[rg] : rg;
    gAp[i] = A + (size_t)arow * DD + c * 8;
    ldsoA[i] = slot * 16;
    gBp[i] = We + (size_t)(n0 + row) * DD + c * 8;
    ldsoB[i] = slot * 16;
  }

  // fragment read offsets (half8 units): row*4 + (quad ^ ((row>>1)&3))
  int aoff[4], boff[4];
#pragma unroll
  for (int i = 0; i < 4; ++i) {
    int m = wm * 64 + i * 16 + r15;
    aoff[i] = m * 4 + (quad ^ ((m >> 1) & 3));
    int n = wq * 64 + i * 16 + r15;
    boff[i] = n * 4 + (quad ^ ((n >> 1) & 3));
  }

  f32x4 acc[4][4];
  f32x4 zero4 = {0.f, 0.f, 0.f, 0.f};
#pragma unroll
  for (int mi = 0; mi < 4; ++mi)
#pragma unroll
    for (int ni = 0; ni < 4; ++ni) acc[mi][ni] = zero4;

#define LDSBUF(B) (lds + (B) * 16384)
#define STAGE(KT, BUF) do {                                          \
    const int ko_ = (KT) * BK;                                       \
    char* lb_ = LDSBUF(BUF);                                         \
    GLDS16(gAp[0] + ko_, lb_ + ldsoA[0]);                            \
    GLDS16(gAp[1] + ko_, lb_ + ldsoA[1]);                            \
    GLDS16(gBp[0] + ko_, lb_ + 8192 + ldsoB[0]);                     \
    GLDS16(gBp[1] + ko_, lb_ + 8192 + ldsoB[1]);                     \
  } while (0)
#define COMPUTE(BUF) do {                                            \
    const half8* AsV = (const half8*)(LDSBUF(BUF));                  \
    const half8* BsV = (const half8*)(LDSBUF(BUF) + 8192);           \
    half8 a_[4], b_[4];                                              \
    _Pragma("unroll")                                                \
    for (int i = 0; i < 4; ++i) a_[i] = AsV[aoff[i]];                \
    _Pragma("unroll")                                                \
    for (int i = 0; i < 4; ++i) b_[i] = BsV[boff[i]];                \
    _Pragma("unroll")                                                \
    for (int mi = 0; mi < 4; ++mi)                                   \
      _Pragma("unroll")                                              \
      for (int ni = 0; ni < 4; ++ni)                                 \
        acc[mi][ni] = __builtin_amdgcn_mfma_f32_16x16x32_f16(a_[mi], b_[ni], acc[mi][ni], 0, 0, 0); \
  } while (0)

  STAGE(0, 0);                         // prologue: fill 2 buffers (8 loads in flight)
  STAGE(1, 1);

  // stage s -> buf s%3 ; compute kt -> buf kt%3. Loop does 30 computes, unrolled x3.
#pragma unroll 1
  for (int kt = 0; kt < NKIT - 2; kt += 3) {
    __builtin_amdgcn_s_waitcnt(WAITCNT_VM4);   // own 4 loads of buf kt landed; kt+1 in flight
    __builtin_amdgcn_s_barrier();
    __asm__ volatile("" ::: "memory");
    STAGE(kt + 2, 2);
    COMPUTE(0);
    __builtin_amdgcn_s_waitcnt(WAITCNT_VM4);
    __builtin_amdgcn_s_barrier();
    __asm__ volatile("" ::: "memory");
    STAGE(kt + 3, 0);
    COMPUTE(1);
    __builtin_amdgcn_s_waitcnt(WAITCNT_VM4);
    __builtin_amdgcn_s_barrier();
    __asm__ volatile("" ::: "memory");
    STAGE(kt + 4, 1);
    COMPUTE(2);
  }
  // tail: computes NKIT-2 (buf 0), NKIT-1 (buf 1); nothing more staged
  __builtin_amdgcn_s_waitcnt(WAITCNT_VM4);
  __builtin_amdgcn_s_barrier();
  __asm__ volatile("" ::: "memory");
  COMPUTE(0);
  __builtin_amdgcn_s_waitcnt(WAITCNT_VM0);
  __builtin_amdgcn_s_barrier();
  __asm__ volatile("" ::: "memory");
  COMPUTE(1);
#undef COMPUTE
#undef STAGE
#undef LDSBUF

  // epilogue. C/D layout: col = lane&15, row = quad*4 + reg
  const float* bptr = bias + (size_t)e * DD;
#pragma unroll
  for (int mi = 0; mi < 4; ++mi) {
    int rowb = m0 + wm * 64 + mi * 16 + quad * 4;
#pragma unroll
    for (int rr = 0; rr < 4; ++rr) {
      int gpos = rowb + rr;
      if (gpos < seg_end) {
        if (MODE == 0) {
#pragma unroll
          for (int ni = 0; ni < 4; ++ni) {
            int n = n0 + wq * 64 + ni * 16 + r15;
            float val = acc[mi][ni][rr] + bptr[n];
            val = 0.5f * val * (1.0f + erff(val * 0.70710678118654752f));
            Hout[(size_t)gpos * DD + n] = (_Float16)val;
          }
        } else {
          int tok = rowtok[gpos];
          float wgl = wgt[tok];
          float* orow = Fout + (size_t)tok * DD;
#pragma unroll
          for (int ni = 0; ni < 4; ++ni) {
            int n = n0 + wq * 64 + ni * 16 + r15;
            orow[n] = (acc[mi][ni][rr] + bptr[n]) * wgl;
          }
        }
      }
    }
  }
}

extern "C" void kernel_launch(void* const* d_in, const int* in_sizes, int n_in,
                              void* d_out, int out_size, void* d_ws, size_t ws_size,
                              hipStream_t stream) {
  const float* x  = (const float*)d_in[0];
  const float* Wg = (const float*)d_in[1];
  const float* bg = (const float*)d_in[2];
  const float* W1 = (const float*)d_in[3];
  const float* b1 = (const float*)d_in[4];
  const float* W2 = (const float*)d_in[5];
  const float* b2 = (const float*)d_in[6];
  float* out = (float*)d_out;

  char* ws = (char*)d_ws;
  const size_t MB16 = (size_t)1 << 24;
  _Float16* W1t = (_Float16*)(ws + 0 * MB16);
  _Float16* W2t = (_Float16*)(ws + 1 * MB16);
  _Float16* xh  = (_Float16*)(ws + 2 * MB16);
  _Float16* H   = (_Float16*)(ws + 3 * MB16);
  int*   assign = (int*)(ws + 4 * MB16);
  int*   rowtok = assign + NT;
  float* wgt    = (float*)(rowtok + NT);
  int*   plan   = (int*)(wgt + NT);    // [1 + 3*MAXTILE]

  prep_kernel<<<4096 + NT / 8, 256, 0, stream>>>(W1, W2, W1t, W2t, x, Wg, bg, assign, wgt, xh);
  sort_kernel<<<1, 1024, 0, stream>>>(assign, rowtok, plan);
  gemm_kernel<0><<<MAXTILE * 8, 256, 0, stream>>>(xh, W1t, b1, plan, H, nullptr, rowtok, nullptr);
  gemm_kernel<1><<<MAXTILE * 8, 256, 0, stream>>>(H, W2t, b2, plan, nullptr, out, rowtok, wgt);
}